// Round 3
// baseline (414.613 us; speedup 1.0000x reference)
//
#include <hip/hip_runtime.h>

// LNKillingRelu: out = where(kf<=0, x, x + kf*d)
//   d[b,g,k,n]  = sum_f W[g,f] x[b,f,k,n]          (bf16 MFMA GEMM, K=512)
//   kf[b,g,n]   = sum_{k,l} x[b,g,k,n] G[k,l] d[b,g,l,n]   (fp32, G = sl3 Killing)
// x: [8,512,8,2048] f32, W: [512,512] f32, out same shape as x.
//
// R3: same decomposition as R2 (128g x 16n per block, 512 thr / 8 waves,
// dbuf chunked LDS, XCD swizzle, in-register epilogue). Staging changed:
//  - x global loads are 2 x dwordx4 per thread (n-contiguous) instead of
//    8 scattered f-strided dwords (global reqs/thread-iter 10 -> 4)
//  - f-packing transpose done via LDS bounce: raw fp32 tile -> scr (dense
//    b128 writes), barrier, 8x conflict-free ds_read_b32 readback + cvt +
//    chunk write. LDS had idle capacity; global request slots did not.
//  - prefetch depth 2 (loads for kt+2 in flight while kt computes).

typedef short bf16x8 __attribute__((ext_vector_type(8)));
typedef float f32x4 __attribute__((ext_vector_type(4)));

__device__ __forceinline__ unsigned short f2bf(float f) {
  unsigned int u = __float_as_uint(f);
  u += 0x7fffu + ((u >> 16) & 1u);   // round-to-nearest-even
  return (unsigned short)(u >> 16);
}

__global__ __launch_bounds__(512, 4) void lnkill_fused(
    const float* __restrict__ x, const float* __restrict__ W,
    float* __restrict__ out) {
  __shared__ __align__(16) short ldsA[2][4096];   // W chunks [kg(4)][m(128)][8]
  __shared__ __align__(16) short ldsB[2][4096];   // x chunks [kg(4)][c(128)][8]
  __shared__ __align__(16) float scr[4096];       // raw x tile [f(32)][k(8)][n(16)]

  const int tid  = threadIdx.x;
  const int lane = tid & 63;
  const int w    = tid >> 6;      // wave 0..7

  // XCD-chunked swizzle: logical l = gt + 4*(nt + 128*b); bid%8 -> XCD
  const int bid = blockIdx.x;                 // 0..4095
  const int l   = (bid & 7) * 512 + (bid >> 3);
  const int gt  = l & 3;
  const int nt  = (l >> 2) & 127;
  const int b   = l >> 9;
  const int g0  = gt * 128;
  const int n0  = nt * 16;

  // x stage-load slots: s = tid and tid+512; s -> f=s>>5, k=(s>>2)&7, q=s&3
  const int sf = tid >> 5;        // 0..15 (slot tid); slot tid+512 -> sf+16
  const int sk = (tid >> 2) & 7;
  const int sq = tid & 3;
  const float* xsl = x + ((size_t)(b * 512 + sf) * 8 + sk) * 2048 + n0 + sq * 4;

  // W stage + readback mapping: cm = tid&127, fg = tid>>7
  const int cm = tid & 127;
  const int fg = tid >> 7;        // 0..3
  const float* Wrow = W + (size_t)(g0 + cm) * 512 + fg * 8;
  const int rb = (cm >> 4) * 16 + (cm & 15);   // k*16 + nn within scr row

  f32x4 acc[8] = {};   // [fn] ; fn == k plane

  float4 xa0, xa1, wa0, wa1;   // set A (tiles 0,2,4,...)
  float4 xb0, xb1, wb0, wb1;   // set B (tiles 1,3,5,...)

  // ---- prologue ----
  // tile 0 -> set A
  {
    const float4* xp = (const float4*)xsl;
    xa0 = xp[0];
    xa1 = *(const float4*)(xsl + (size_t)16 * 16384);
    const float4* wp = (const float4*)Wrow;
    wa0 = wp[0]; wa1 = wp[1];
  }
  // raw-write x tile0 to scr ; W tile0 direct to ldsA[0]
  *(float4*)&scr[4 * tid]         = xa0;
  *(float4*)&scr[4 * (tid + 512)] = xa1;
  {
    float wf[8] = {wa0.x, wa0.y, wa0.z, wa0.w, wa1.x, wa1.y, wa1.z, wa1.w};
    bf16x8 va;
#pragma unroll
    for (int j = 0; j < 8; ++j) va[j] = (short)f2bf(wf[j]);
    *(bf16x8*)&ldsA[0][(fg * 128 + cm) * 8] = va;
  }
  __syncthreads();
  // readback scr -> chunk-write ldsB[0]
  {
    bf16x8 vb;
#pragma unroll
    for (int j = 0; j < 8; ++j) vb[j] = (short)f2bf(scr[(fg * 8 + j) * 128 + rb]);
    *(bf16x8*)&ldsB[0][(fg * 128 + cm) * 8] = vb;
  }
  // tile 1 -> set B (issued, consumed at iter 0)
  {
    const float* xp1 = xsl + (size_t)32 * 16384;
    xb0 = *(const float4*)xp1;
    xb1 = *(const float4*)(xp1 + (size_t)16 * 16384);
    const float4* wp = (const float4*)(Wrow + 32);
    wb0 = wp[0]; wb1 = wp[1];
  }
  __syncthreads();

  const int klane = lane >> 4;
  const int li    = lane & 15;

  for (int kt = 0; kt < 16; ++kt) {
    const int cur = kt & 1;

    // issue loads for tile kt+2 into set[kt&1] (depth-2 prefetch)
    if (kt < 14) {
      const float* xp = xsl + (size_t)(kt + 2) * 32 * 16384;
      const float4* wp = (const float4*)(Wrow + (kt + 2) * 32);
      if (cur == 0) {
        xa0 = *(const float4*)xp;
        xa1 = *(const float4*)(xp + (size_t)16 * 16384);
        wa0 = wp[0]; wa1 = wp[1];
      } else {
        xb0 = *(const float4*)xp;
        xb1 = *(const float4*)(xp + (size_t)16 * 16384);
        wb0 = wp[0]; wb1 = wp[1];
      }
    }

    // compute from buf[cur] (dense 16B chunks, conflict-free)
    {
      const short* Ac = ldsA[cur];
      const short* Bc = ldsB[cur];
      bf16x8 afr = *(const bf16x8*)&Ac[(klane * 128 + w * 16 + li) * 8];
#pragma unroll
      for (int fn = 0; fn < 8; ++fn) {
        bf16x8 bfr = *(const bf16x8*)&Bc[(klane * 128 + fn * 16 + li) * 8];
        acc[fn] = __builtin_amdgcn_mfma_f32_16x16x32_bf16(afr, bfr, acc[fn], 0, 0, 0);
      }
    }

    // stage tile kt+1 (in set[(kt+1)&1]) into buf[cur^1]
    if (kt < 15) {
      const int nxt = cur ^ 1;
      float4 x0, x1, w0, w1;
      if (cur == 0) { x0 = xb0; x1 = xb1; w0 = wb0; w1 = wb1; }
      else          { x0 = xa0; x1 = xa1; w0 = wa0; w1 = wa1; }
      // raw-write x to scr ; W direct chunk-write
      *(float4*)&scr[4 * tid]         = x0;
      *(float4*)&scr[4 * (tid + 512)] = x1;
      {
        float wf[8] = {w0.x, w0.y, w0.z, w0.w, w1.x, w1.y, w1.z, w1.w};
        bf16x8 va;
#pragma unroll
        for (int j = 0; j < 8; ++j) va[j] = (short)f2bf(wf[j]);
        *(bf16x8*)&ldsA[nxt][(fg * 128 + cm) * 8] = va;
      }
      __syncthreads();
      {
        bf16x8 vb;
#pragma unroll
        for (int j = 0; j < 8; ++j) vb[j] = (short)f2bf(scr[(fg * 8 + j) * 128 + rb]);
        *(bf16x8*)&ldsB[nxt][(fg * 128 + cm) * 8] = vb;
      }
      __syncthreads();
    }
  }

  // ---- epilogue: kf (fp32 x, Killing Gram) + branch + store, in-register ----
  // D frag: col = li (nn), row = klane*4 + r  (within the wave's 16 g-rows)
#pragma unroll
  for (int r = 0; r < 4; ++r) {
    const int g = g0 + w * 16 + klane * 4 + r;
    const size_t base = ((size_t)(b * 512 + g)) * 16384 + n0 + li;
    float xk[8];
#pragma unroll
    for (int k = 0; k < 8; ++k) xk[k] = x[base + (size_t)k * 2048];
    // c_l = (G x)_l ; G: 12@(0,0),(4,4); -6@(0,4); 6@{1,3},{2,6},{5,7}
    const float c0 = 12.f * xk[0] - 6.f * xk[4];
    const float c4 = 12.f * xk[4] - 6.f * xk[0];
    const float c1 = 6.f * xk[3];
    const float c2 = 6.f * xk[6];
    const float c3 = 6.f * xk[1];
    const float c5 = 6.f * xk[7];
    const float c6 = 6.f * xk[2];
    const float c7 = 6.f * xk[5];
    const float kf = c0 * acc[0][r] + c1 * acc[1][r]
                   + c2 * acc[2][r] + c3 * acc[3][r]
                   + c4 * acc[4][r] + c5 * acc[5][r]
                   + c6 * acc[6][r] + c7 * acc[7][r];
#pragma unroll
    for (int k = 0; k < 8; ++k) {
      const float o = (kf <= 0.f) ? xk[k] : fmaf(kf, acc[k][r], xk[k]);
      out[base + (size_t)k * 2048] = o;
    }
  }
}

extern "C" void kernel_launch(void* const* d_in, const int* in_sizes, int n_in,
                              void* d_out, int out_size, void* d_ws, size_t ws_size,
                              hipStream_t stream) {
  const float* x = (const float*)d_in[0];
  const float* W = (const float*)d_in[1];
  float* out = (float*)d_out;
  // 1D grid, swizzled in-kernel: 4 g-tiles x 128 n-tiles x 8 batches = 4096
  lnkill_fused<<<dim3(4096), dim3(512), 0, stream>>>(x, W, out);
}

// Round 4
// 402.760 us; speedup vs baseline: 1.0294x; 1.0294x over previous
//
#include <hip/hip_runtime.h>

// LNKillingRelu: out = where(kf<=0, x, x + kf*d)
//   d[b,g,k,n]  = sum_f W[g,f] x[b,f,k,n]          (bf16 MFMA GEMM, K=512)
//   kf[b,g,n]   = sum_{k,l} x[b,g,k,n] G[k,l] d[b,g,l,n]   (fp32, G = sl3 Killing)
// x: [8,512,8,2048] f32, W: [512,512] f32, out same shape as x.
//
// R4 = R2 structure (128g x 16n/block, 512thr/8 waves, chunked dbuf LDS, XCD
// swizzle, in-register Killing epilogue) + NON-DRAINING pipeline:
//  - raw s_barrier with lgkmcnt(0)-only wait (NO vmcnt drain at barriers;
//    __syncthreads forces vmcnt(0) -> 16x exposed HBM latency was the R2/R3 wall)
//  - depth-2 register rotation: tile kt+2 loads issued at iter kt, staged at
//    iter kt+1 -> each wave keeps ~10-20 VMEM insts in flight across barriers.

typedef short bf16x8 __attribute__((ext_vector_type(8)));
typedef float f32x4 __attribute__((ext_vector_type(4)));

__device__ __forceinline__ unsigned short f2bf(float f) {
  unsigned int u = __float_as_uint(f);
  u += 0x7fffu + ((u >> 16) & 1u);   // round-to-nearest-even
  return (unsigned short)(u >> 16);
}

__device__ __forceinline__ void block_sync_nodrain() {
  // LDS writes visible to the workgroup, but vmcnt deliberately NOT drained:
  // global prefetch loads stay in flight across the barrier.
  asm volatile("s_waitcnt lgkmcnt(0)" ::: "memory");
  __builtin_amdgcn_s_barrier();
  __builtin_amdgcn_sched_barrier(0);
}

__global__ __launch_bounds__(512, 4) void lnkill_fused(
    const float* __restrict__ x, const float* __restrict__ W,
    float* __restrict__ out) {
  // chunked LDS: [buf][kg(4)][row(128)][8 bf16] -> dense 16B, conflict-free
  __shared__ __align__(16) short ldsA[2][4096];   // W tile
  __shared__ __align__(16) short ldsB[2][4096];   // x tile

  const int tid  = threadIdx.x;
  const int lane = tid & 63;
  const int w    = tid >> 6;      // wave 0..7

  // XCD-chunked swizzle: logical l = gt + 4*(nt + 128*b); bid%8 -> XCD
  const int bid = blockIdx.x;                 // 0..4095
  const int l   = (bid & 7) * 512 + (bid >> 3);
  const int gt  = l & 3;
  const int nt  = (l >> 2) & 127;
  const int b   = l >> 9;
  const int g0  = gt * 128;
  const int n0  = nt * 16;

  // staging map: cm = col (B) / row (A), fg = f-subgroup of 8
  const int cm = tid & 127;
  const int fg = tid >> 7;        // 0..3
  const float* xs   = x + (((size_t)(b * 512 + fg * 8)) * 8 + (cm >> 4)) * 2048
                        + n0 + (cm & 15);
  const float* Wrow = W + (size_t)(g0 + cm) * 512 + fg * 8;

  f32x4 acc[8] = {};   // [fn]; fn == k plane

  // depth-2 rotation register sets: tile t lives in set[t&1]
  float  xA[8], xB[8];
  float4 wA0, wA1, wB0, wB1;

  // ---- prologue ----
  // tile 0 -> set A
#pragma unroll
  for (int j = 0; j < 8; ++j) xA[j] = xs[(size_t)j * 16384];
  {
    const float4* wp = (const float4*)Wrow;
    wA0 = wp[0]; wA1 = wp[1];
  }
  // stage tile 0 -> buf 0 (cvt waits on tile-0 loads only)
  {
    float wf[8] = {wA0.x, wA0.y, wA0.z, wA0.w, wA1.x, wA1.y, wA1.z, wA1.w};
    bf16x8 vb, va;
#pragma unroll
    for (int j = 0; j < 8; ++j) {
      vb[j] = (short)f2bf(xA[j]);
      va[j] = (short)f2bf(wf[j]);
    }
    *(bf16x8*)&ldsB[0][(fg * 128 + cm) * 8] = vb;
    *(bf16x8*)&ldsA[0][(fg * 128 + cm) * 8] = va;
  }
  // tile 1 -> set B (stays in flight across the barrier)
#pragma unroll
  for (int j = 0; j < 8; ++j) xB[j] = xs[(size_t)(32 + j) * 16384];
  {
    const float4* wp = (const float4*)(Wrow + 32);
    wB0 = wp[0]; wB1 = wp[1];
  }
  block_sync_nodrain();

  const int klane = lane >> 4;
  const int li    = lane & 15;

  for (int kt = 0; kt < 16; ++kt) {
    const int cur = kt & 1;

    // issue tile kt+2 into set[cur] (tile kt's raw regs were consumed at
    // the end of iter kt-1; set[cur] is free)
    if (kt < 14) {
      const float* xp = xs + (size_t)(kt + 2) * 32 * 16384;
      const float4* wp = (const float4*)(Wrow + (kt + 2) * 32);
      if (cur == 0) {
#pragma unroll
        for (int j = 0; j < 8; ++j) xA[j] = xp[(size_t)j * 16384];
        wA0 = wp[0]; wA1 = wp[1];
      } else {
#pragma unroll
        for (int j = 0; j < 8; ++j) xB[j] = xp[(size_t)j * 16384];
        wB0 = wp[0]; wB1 = wp[1];
      }
    }

    // compute tile kt from buf[cur] (dense 16B chunk reads, conflict-free)
    {
      const short* Ac = ldsA[cur];
      const short* Bc = ldsB[cur];
      bf16x8 afr = *(const bf16x8*)&Ac[(klane * 128 + w * 16 + li) * 8];
#pragma unroll
      for (int fn = 0; fn < 8; ++fn) {
        bf16x8 bfr = *(const bf16x8*)&Bc[(klane * 128 + fn * 16 + li) * 8];
        acc[fn] = __builtin_amdgcn_mfma_f32_16x16x32_bf16(afr, bfr, acc[fn], 0, 0, 0);
      }
    }

    // stage tile kt+1 (loaded one full iteration ago) into buf[cur^1]
    if (kt < 15) {
      const int nxt = cur ^ 1;
      float xr[8]; float4 w0, w1;
      if (cur == 0) {
#pragma unroll
        for (int j = 0; j < 8; ++j) xr[j] = xB[j];
        w0 = wB0; w1 = wB1;
      } else {
#pragma unroll
        for (int j = 0; j < 8; ++j) xr[j] = xA[j];
        w0 = wA0; w1 = wA1;
      }
      float wf[8] = {w0.x, w0.y, w0.z, w0.w, w1.x, w1.y, w1.z, w1.w};
      bf16x8 vb, va;
#pragma unroll
      for (int j = 0; j < 8; ++j) {
        vb[j] = (short)f2bf(xr[j]);
        va[j] = (short)f2bf(wf[j]);
      }
      *(bf16x8*)&ldsB[nxt][(fg * 128 + cm) * 8] = vb;
      *(bf16x8*)&ldsA[nxt][(fg * 128 + cm) * 8] = va;
      block_sync_nodrain();
    }
  }

  // ---- epilogue: kf (fp32 x, Killing Gram) + branch + store, in-register ----
  // D frag: col = li (nn), row = klane*4 + r (within the wave's 16 g-rows)
#pragma unroll
  for (int r = 0; r < 4; ++r) {
    const int g = g0 + w * 16 + klane * 4 + r;
    const size_t base = ((size_t)(b * 512 + g)) * 16384 + n0 + li;
    float xk[8];
#pragma unroll
    for (int k = 0; k < 8; ++k) xk[k] = x[base + (size_t)k * 2048];
    // c_l = (G x)_l ; G: 12@(0,0),(4,4); -6@(0,4); 6@{1,3},{2,6},{5,7}
    const float c0 = 12.f * xk[0] - 6.f * xk[4];
    const float c4 = 12.f * xk[4] - 6.f * xk[0];
    const float c1 = 6.f * xk[3];
    const float c2 = 6.f * xk[6];
    const float c3 = 6.f * xk[1];
    const float c5 = 6.f * xk[7];
    const float c6 = 6.f * xk[2];
    const float c7 = 6.f * xk[5];
    const float kf = c0 * acc[0][r] + c1 * acc[1][r]
                   + c2 * acc[2][r] + c3 * acc[3][r]
                   + c4 * acc[4][r] + c5 * acc[5][r]
                   + c6 * acc[6][r] + c7 * acc[7][r];
#pragma unroll
    for (int k = 0; k < 8; ++k) {
      const float o = (kf <= 0.f) ? xk[k] : fmaf(kf, acc[k][r], xk[k]);
      out[base + (size_t)k * 2048] = o;
    }
  }
}

extern "C" void kernel_launch(void* const* d_in, const int* in_sizes, int n_in,
                              void* d_out, int out_size, void* d_ws, size_t ws_size,
                              hipStream_t stream) {
  const float* x = (const float*)d_in[0];
  const float* W = (const float*)d_in[1];
  float* out = (float*)d_out;
  // 1D grid, swizzled in-kernel: 4 g-tiles x 128 n-tiles x 8 batches = 4096
  lnkill_fused<<<dim3(4096), dim3(512), 0, stream>>>(x, W, out);
}

// Round 5
// 307.898 us; speedup vs baseline: 1.3466x; 1.3081x over previous
//
#include <hip/hip_runtime.h>

// LNKillingRelu: out = where(kf<=0, x, x + kf*d)
//   d[b,g,k,n]  = sum_f W[g,f] x[b,f,k,n]          (bf16 MFMA GEMM, K=512)
//   kf[b,g,n]   = sum_{k,l} x[b,g,k,n] G[k,l] d[b,g,l,n]   (fp32, G = sl3 Killing)
// x: [8,512,8,2048] f32, W: [512,512] f32, out same shape as x.
//
// R5: kill the staging wall (R1-R4 invariant ~4200 cy/block-iter: scattered W
// loads ~1024 TA reqs/iter + ~1100 VALU-cy/iter of f32->bf16 cvt).
//  - prepass packs W (512KB) + x (128MiB) as bf16 in per-block tile layout in d_ws
//  - main kernel stages via global_load_lds dwordx4 (2 insts/thread/iter,
//    coalesced, no cvt), 4-buffer depth-2 pipeline, counted vmcnt BEFORE raw
//    s_barrier (loads for t+1,t+2 in flight across barriers)
//  - epilogue reads x as bf16 from packed buffer (L2-hot; error << threshold)
//  - fallback to proven R2 kernel if ws_size too small.

typedef short bf16x8 __attribute__((ext_vector_type(8)));
typedef float f32x4 __attribute__((ext_vector_type(4)));

__device__ __forceinline__ unsigned short f2bf(float f) {
  unsigned int u = __float_as_uint(f);
  u += 0x7fffu + ((u >> 16) & 1u);   // round-to-nearest-even
  return (unsigned short)(u >> 16);
}

__device__ __forceinline__ float bfu(unsigned short u) {
  return __uint_as_float(((unsigned int)u) << 16);
}

__device__ __forceinline__ void gload16(const void* g, void* l) {
  typedef const __attribute__((address_space(1))) unsigned int* gp_t;
  typedef __attribute__((address_space(3))) unsigned int* lp_t;
  __builtin_amdgcn_global_load_lds((gp_t)g, (lp_t)l, 16, 0, 0);
}

// ---------------- prepass: pack x -> bf16 tiles ----------------
// layout: chunk cid = (((b*128+nt)*16+kt)*4+kg)*128 + c ; element = cid*8 + j
//   where c = k*16+nn, f = kt*32+kg*8+j. Per (b,nt,kt): one 8KB LDS-ready tile.
__global__ __launch_bounds__(256) void prepack_x(const float* __restrict__ x,
                                                 short* __restrict__ xp) {
  const int cid = blockIdx.x * 256 + threadIdx.x;    // 8,388,608 chunks
  const int c = cid & 127;
  int t = cid >> 7;
  const int kg = t & 3;  t >>= 2;
  const int kt = t & 15; t >>= 4;
  const int nt = t & 127; t >>= 7;
  const int b = t;
  const int f0 = kt * 32 + kg * 8;
  const float* src = x + ((size_t)(b * 512 + f0) * 8 + (c >> 4)) * 2048
                       + nt * 16 + (c & 15);
  bf16x8 v;
#pragma unroll
  for (int j = 0; j < 8; ++j) v[j] = (short)f2bf(src[(size_t)j * 16384]);
  *(bf16x8*)&xp[(size_t)cid * 8] = v;
}

// ---------------- prepass: pack W -> bf16 tiles ----------------
// chunk cid = ((gt*16+kt)*4+kg)*128 + m ; element = cid*8 + j ; f = kt*32+kg*8+j
__global__ __launch_bounds__(256) void prepack_w(const float* __restrict__ W,
                                                 short* __restrict__ wp) {
  const int cid = blockIdx.x * 256 + threadIdx.x;    // 32768 chunks
  const int m = cid & 127;
  int t = cid >> 7;
  const int kg = t & 3;  t >>= 2;
  const int kt = t & 15; t >>= 4;
  const int gt = t;
  const float* src = W + (size_t)(gt * 128 + m) * 512 + kt * 32 + kg * 8;
  bf16x8 v;
#pragma unroll
  for (int j = 0; j < 8; ++j) v[j] = (short)f2bf(src[j]);
  *(bf16x8*)&wp[(size_t)cid * 8] = v;
}

// ---------------- main fused GEMM + Killing epilogue ----------------
__global__ __launch_bounds__(512, 4) void lnkill_gemm_pk(
    const short* __restrict__ xp, const short* __restrict__ wp,
    float* __restrict__ out) {
  __shared__ __align__(16) short ldsA[4][4096];   // W tiles, buf = tile&3
  __shared__ __align__(16) short ldsB[4][4096];   // x tiles

  const int tid  = threadIdx.x;
  const int lane = tid & 63;
  const int w    = tid >> 6;      // wave 0..7

  // XCD-chunked swizzle: logical l = gt + 4*(nt + 128*b)
  const int bid = blockIdx.x;                 // 0..4095
  const int l   = (bid & 7) * 512 + (bid >> 3);
  const int gt  = l & 3;
  const int nt  = (l >> 2) & 127;
  const int b   = l >> 9;
  const int g0  = gt * 128;
  const int n0  = nt * 16;

  // staging sources (shorts); tile t adds t*4096
  const short* xsrc = xp + ((size_t)(b * 128 + nt) * 16) * 4096 + w * 512 + lane * 8;
  const short* wsrc = wp + ((size_t)gt * 16) * 4096 + w * 512 + lane * 8;

  f32x4 acc[8] = {};   // [fn]; fn == k plane

  // prologue: tiles 0,1 in flight
  gload16(wsrc,        &ldsA[0][w * 512]);
  gload16(xsrc,        &ldsB[0][w * 512]);
  gload16(wsrc + 4096, &ldsA[1][w * 512]);
  gload16(xsrc + 4096, &ldsB[1][w * 512]);

  const int klane = lane >> 4;
  const int li    = lane & 15;

#pragma unroll
  for (int kt = 0; kt < 16; ++kt) {
    // issue tile kt+2 -> buf[(kt+2)&3] (held tile kt-2, read two barriers ago)
    if (kt < 14) {
      gload16(wsrc + (size_t)(kt + 2) * 4096, &ldsA[(kt + 2) & 3][w * 512]);
      gload16(xsrc + (size_t)(kt + 2) * 4096, &ldsB[(kt + 2) & 3][w * 512]);
      // my slice of tile kt landed (tiles kt+1,kt+2 = 4 loads stay in flight)
      asm volatile("s_waitcnt vmcnt(4)" ::: "memory");
    } else if (kt == 14) {
      asm volatile("s_waitcnt vmcnt(2)" ::: "memory");
    } else {
      asm volatile("s_waitcnt vmcnt(0)" ::: "memory");
    }
    __builtin_amdgcn_s_barrier();      // all waves' slices of tile kt landed
    __builtin_amdgcn_sched_barrier(0);

    const short* Ac = ldsA[kt & 3];
    const short* Bc = ldsB[kt & 3];
    bf16x8 afr = *(const bf16x8*)&Ac[(klane * 128 + w * 16 + li) * 8];
#pragma unroll
    for (int fn = 0; fn < 8; ++fn) {
      bf16x8 bfr = *(const bf16x8*)&Bc[(klane * 128 + fn * 16 + li) * 8];
      acc[fn] = __builtin_amdgcn_mfma_f32_16x16x32_bf16(afr, bfr, acc[fn], 0, 0, 0);
    }
  }

  // ---- epilogue: kf (Killing Gram) + branch + store; x from packed bf16 ----
  // D frag: col = li (nn), row = klane*4 + r (within the wave's 16 g-rows)
  const unsigned short* xpu = (const unsigned short*)xp;
  const size_t cb0 = ((size_t)(b * 128 + nt) * 16) * 4096;  // (b,nt) region, shorts
#pragma unroll
  for (int r = 0; r < 4; ++r) {
    const int wr = w * 16 + klane * 4 + r;   // row within 128
    const int g  = g0 + wr;
    const size_t base = ((size_t)(b * 512 + g)) * 16384 + n0 + li;
    const size_t ch = cb0 + (size_t)((g >> 5) * 4 + ((wr >> 3) & 3)) * 1024;
    const int jj = wr & 7;
    float xk[8];
#pragma unroll
    for (int k = 0; k < 8; ++k)
      xk[k] = bfu(xpu[ch + (size_t)(k * 16 + li) * 8 + jj]);
    // c_l = (G x)_l ; G: 12@(0,0),(4,4); -6@(0,4); 6@{1,3},{2,6},{5,7}
    const float c0 = 12.f * xk[0] - 6.f * xk[4];
    const float c4 = 12.f * xk[4] - 6.f * xk[0];
    const float c1 = 6.f * xk[3];
    const float c2 = 6.f * xk[6];
    const float c3 = 6.f * xk[1];
    const float c5 = 6.f * xk[7];
    const float c6 = 6.f * xk[2];
    const float c7 = 6.f * xk[5];
    const float kf = c0 * acc[0][r] + c1 * acc[1][r]
                   + c2 * acc[2][r] + c3 * acc[3][r]
                   + c4 * acc[4][r] + c5 * acc[5][r]
                   + c6 * acc[6][r] + c7 * acc[7][r];
#pragma unroll
    for (int k = 0; k < 8; ++k) {
      const float o = (kf <= 0.f) ? xk[k] : fmaf(kf, acc[k][r], xk[k]);
      out[base + (size_t)k * 2048] = o;
    }
  }
}

// ---------------- fallback: proven R2 kernel (ws too small) ----------------
__global__ __launch_bounds__(512, 4) void lnkill_fused(
    const float* __restrict__ x, const float* __restrict__ W,
    float* __restrict__ out) {
  __shared__ __align__(16) short ldsA[2][4096];
  __shared__ __align__(16) short ldsB[2][4096];

  const int tid  = threadIdx.x;
  const int lane = tid & 63;
  const int w    = tid >> 6;

  const int bid = blockIdx.x;
  const int l   = (bid & 7) * 512 + (bid >> 3);
  const int gt  = l & 3;
  const int nt  = (l >> 2) & 127;
  const int b   = l >> 9;
  const int g0  = gt * 128;
  const int n0  = nt * 16;

  const int cm = tid & 127;
  const int fg = tid >> 7;
  const float* xs   = x + (((size_t)(b * 512 + fg * 8)) * 8 + (cm >> 4)) * 2048
                        + n0 + (cm & 15);
  const float* Wrow = W + (size_t)(g0 + cm) * 512 + fg * 8;

  f32x4 acc[8] = {};

  {
    float xv[8];
#pragma unroll
    for (int j = 0; j < 8; ++j) xv[j] = xs[(size_t)j * 16384];
    float4 wv[2];
    const float4* wp = (const float4*)Wrow;
    wv[0] = wp[0]; wv[1] = wp[1];
    const float* wf = (const float*)wv;
    bf16x8 vb, va;
#pragma unroll
    for (int j = 0; j < 8; ++j) {
      vb[j] = (short)f2bf(xv[j]);
      va[j] = (short)f2bf(wf[j]);
    }
    *(bf16x8*)&ldsB[0][(fg * 128 + cm) * 8] = vb;
    *(bf16x8*)&ldsA[0][(fg * 128 + cm) * 8] = va;
  }
  __syncthreads();

  const int klane = lane >> 4;
  const int li    = lane & 15;

  for (int kt = 0; kt < 16; ++kt) {
    const int cur = kt & 1;
    float xv[8];
    float4 wv[2];
    if (kt < 15) {
      const float* xpn = xs + (size_t)(kt + 1) * 32 * 16384;
#pragma unroll
      for (int j = 0; j < 8; ++j) xv[j] = xpn[(size_t)j * 16384];
      const float4* wp = (const float4*)(Wrow + (kt + 1) * 32);
      wv[0] = wp[0]; wv[1] = wp[1];
    }
    {
      const short* Ac = ldsA[cur];
      const short* Bc = ldsB[cur];
      bf16x8 afr = *(const bf16x8*)&Ac[(klane * 128 + w * 16 + li) * 8];
#pragma unroll
      for (int fn = 0; fn < 8; ++fn) {
        bf16x8 bfr = *(const bf16x8*)&Bc[(klane * 128 + fn * 16 + li) * 8];
        acc[fn] = __builtin_amdgcn_mfma_f32_16x16x32_bf16(afr, bfr, acc[fn], 0, 0, 0);
      }
    }
    if (kt < 15) {
      const int nxt = cur ^ 1;
      const float* wf = (const float*)wv;
      bf16x8 vb, va;
#pragma unroll
      for (int j = 0; j < 8; ++j) {
        vb[j] = (short)f2bf(xv[j]);
        va[j] = (short)f2bf(wf[j]);
      }
      __syncthreads();
      *(bf16x8*)&ldsB[nxt][(fg * 128 + cm) * 8] = vb;
      *(bf16x8*)&ldsA[nxt][(fg * 128 + cm) * 8] = va;
      __syncthreads();
    }
  }

#pragma unroll
  for (int r = 0; r < 4; ++r) {
    const int g = g0 + w * 16 + klane * 4 + r;
    const size_t base = ((size_t)(b * 512 + g)) * 16384 + n0 + li;
    float xk[8];
#pragma unroll
    for (int k = 0; k < 8; ++k) xk[k] = x[base + (size_t)k * 2048];
    const float c0 = 12.f * xk[0] - 6.f * xk[4];
    const float c4 = 12.f * xk[4] - 6.f * xk[0];
    const float c1 = 6.f * xk[3];
    const float c2 = 6.f * xk[6];
    const float c3 = 6.f * xk[1];
    const float c5 = 6.f * xk[7];
    const float c6 = 6.f * xk[2];
    const float c7 = 6.f * xk[5];
    const float kf = c0 * acc[0][r] + c1 * acc[1][r]
                   + c2 * acc[2][r] + c3 * acc[3][r]
                   + c4 * acc[4][r] + c5 * acc[5][r]
                   + c6 * acc[6][r] + c7 * acc[7][r];
#pragma unroll
    for (int k = 0; k < 8; ++k) {
      const float o = (kf <= 0.f) ? xk[k] : fmaf(kf, acc[k][r], xk[k]);
      out[base + (size_t)k * 2048] = o;
    }
  }
}

extern "C" void kernel_launch(void* const* d_in, const int* in_sizes, int n_in,
                              void* d_out, int out_size, void* d_ws, size_t ws_size,
                              hipStream_t stream) {
  const float* x = (const float*)d_in[0];
  const float* W = (const float*)d_in[1];
  float* out = (float*)d_out;

  const size_t need = (size_t)512 * 1024 + (size_t)8388608 * 16;  // 0.5MB + 128MiB
  if (ws_size >= need) {
    short* wp = (short*)d_ws;                       // 512 KB
    short* xp = (short*)d_ws + 262144;              // after 512 KB
    prepack_w<<<dim3(128),   dim3(256), 0, stream>>>(W, wp);
    prepack_x<<<dim3(32768), dim3(256), 0, stream>>>(x, xp);
    lnkill_gemm_pk<<<dim3(4096), dim3(512), 0, stream>>>(xp, wp, out);
  } else {
    lnkill_fused<<<dim3(4096), dim3(512), 0, stream>>>(x, W, out);
  }
}

// Round 6
// 277.390 us; speedup vs baseline: 1.4947x; 1.1100x over previous
//
#include <hip/hip_runtime.h>

// LNKillingRelu: out = where(kf<=0, x, x + kf*d)
//   d[b,g,k,n]  = sum_f W[g,f] x[b,f,k,n]          (bf16 MFMA GEMM, K=512)
//   kf[b,g,n]   = sum_{k,l} x[b,g,k,n] G[k,l] d[b,g,l,n]   (fp32, G = sl3 Killing)
// x: [8,512,8,2048] f32, W: [512,512] f32, out same shape as x.
//
// R6 = R5 (prepacked bf16 tiles + global_load_lds staging + counted-vmcnt
// raw-barrier pipeline) with:
//  (a) depth-3 prefetch, 5 LDS buffers (80 KB; buffers >= depth+2 so the
//      tile kt+3 write only lands in a buffer whose readers finished before
//      barrier(kt-1)); vmcnt(6) steady state -> 3 tiles in flight.
//  (b) epilogue reads ORIGINAL f32 x (64B-coalesced, 4 lines/inst) instead of
//      2B-stride-16B gathers from xp (16 lines/inst, ~512 TA reqs/wave).
//      BW headroom is 3x, TA/latency is the wall -> trade bytes for requests.

typedef short bf16x8 __attribute__((ext_vector_type(8)));
typedef float f32x4 __attribute__((ext_vector_type(4)));

__device__ __forceinline__ unsigned short f2bf(float f) {
  unsigned int u = __float_as_uint(f);
  u += 0x7fffu + ((u >> 16) & 1u);   // round-to-nearest-even
  return (unsigned short)(u >> 16);
}

__device__ __forceinline__ void gload16(const void* g, void* l) {
  typedef const __attribute__((address_space(1))) unsigned int* gp_t;
  typedef __attribute__((address_space(3))) unsigned int* lp_t;
  __builtin_amdgcn_global_load_lds((gp_t)g, (lp_t)l, 16, 0, 0);
}

// ---------------- prepass: pack x -> bf16 tiles ----------------
// chunk cid = (((b*128+nt)*16+kt)*4+kg)*128 + c ; element = cid*8 + j
//   where c = k*16+nn, f = kt*32+kg*8+j. Per (b,nt,kt): one 8KB LDS-ready tile.
__global__ __launch_bounds__(256) void prepack_x(const float* __restrict__ x,
                                                 short* __restrict__ xp) {
  const int cid = blockIdx.x * 256 + threadIdx.x;    // 8,388,608 chunks
  const int c = cid & 127;
  int t = cid >> 7;
  const int kg = t & 3;  t >>= 2;
  const int kt = t & 15; t >>= 4;
  const int nt = t & 127; t >>= 7;
  const int b = t;
  const int f0 = kt * 32 + kg * 8;
  const float* src = x + ((size_t)(b * 512 + f0) * 8 + (c >> 4)) * 2048
                       + nt * 16 + (c & 15);
  bf16x8 v;
#pragma unroll
  for (int j = 0; j < 8; ++j) v[j] = (short)f2bf(src[(size_t)j * 16384]);
  *(bf16x8*)&xp[(size_t)cid * 8] = v;
}

// ---------------- prepass: pack W -> bf16 tiles ----------------
// chunk cid = ((gt*16+kt)*4+kg)*128 + m ; element = cid*8 + j ; f = kt*32+kg*8+j
__global__ __launch_bounds__(256) void prepack_w(const float* __restrict__ W,
                                                 short* __restrict__ wp) {
  const int cid = blockIdx.x * 256 + threadIdx.x;    // 32768 chunks
  const int m = cid & 127;
  int t = cid >> 7;
  const int kg = t & 3;  t >>= 2;
  const int kt = t & 15; t >>= 4;
  const int gt = t;
  const float* src = W + (size_t)(gt * 128 + m) * 512 + kt * 32 + kg * 8;
  bf16x8 v;
#pragma unroll
  for (int j = 0; j < 8; ++j) v[j] = (short)f2bf(src[j]);
  *(bf16x8*)&wp[(size_t)cid * 8] = v;
}

// ---------------- main fused GEMM + Killing epilogue ----------------
__global__ __launch_bounds__(512, 4) void lnkill_gemm_pk(
    const short* __restrict__ xp, const short* __restrict__ wp,
    const float* __restrict__ x, float* __restrict__ out) {
  __shared__ __align__(16) short ldsA[5][4096];   // W tiles, buf = tile % 5
  __shared__ __align__(16) short ldsB[5][4096];   // x tiles

  const int tid  = threadIdx.x;
  const int lane = tid & 63;
  const int w    = tid >> 6;      // wave 0..7

  // XCD-chunked swizzle: logical l = gt + 4*(nt + 128*b)
  const int bid = blockIdx.x;                 // 0..4095
  const int l   = (bid & 7) * 512 + (bid >> 3);
  const int gt  = l & 3;
  const int nt  = (l >> 2) & 127;
  const int b   = l >> 9;
  const int g0  = gt * 128;
  const int n0  = nt * 16;

  // staging sources (shorts); tile t adds t*4096
  const short* xsrc = xp + ((size_t)(b * 128 + nt) * 16) * 4096 + w * 512 + lane * 8;
  const short* wsrc = wp + ((size_t)gt * 16) * 4096 + w * 512 + lane * 8;

  f32x4 acc[8] = {};   // [fn]; fn == k plane

  // prologue: tiles 0,1,2 in flight (6 loads/wave)
  gload16(wsrc,        &ldsA[0][w * 512]);
  gload16(xsrc,        &ldsB[0][w * 512]);
  gload16(wsrc + 4096, &ldsA[1][w * 512]);
  gload16(xsrc + 4096, &ldsB[1][w * 512]);
  gload16(wsrc + 8192, &ldsA[2][w * 512]);
  gload16(xsrc + 8192, &ldsB[2][w * 512]);

  const int klane = lane >> 4;
  const int li    = lane & 15;

#pragma unroll
  for (int kt = 0; kt < 16; ++kt) {
    // issue tile kt+3 -> buf (kt+3)%5. That buffer last held tile kt-2, whose
    // readers all finished before barrier(kt-1) (< this issue point). Safe.
    if (kt <= 12) {
      gload16(wsrc + (size_t)(kt + 3) * 4096, &ldsA[(kt + 3) % 5][w * 512]);
      gload16(xsrc + (size_t)(kt + 3) * 4096, &ldsB[(kt + 3) % 5][w * 512]);
      // tiles kt+1..kt+3 (6 loads) stay in flight; wait only for tile kt.
      asm volatile("s_waitcnt vmcnt(6)" ::: "memory");
    } else if (kt == 13) {
      asm volatile("s_waitcnt vmcnt(4)" ::: "memory");
    } else if (kt == 14) {
      asm volatile("s_waitcnt vmcnt(2)" ::: "memory");
    } else {
      asm volatile("s_waitcnt vmcnt(0)" ::: "memory");
    }
    __builtin_amdgcn_s_barrier();      // all waves' slices of tile kt landed
    __builtin_amdgcn_sched_barrier(0);

    const short* Ac = ldsA[kt % 5];
    const short* Bc = ldsB[kt % 5];
    bf16x8 afr = *(const bf16x8*)&Ac[(klane * 128 + w * 16 + li) * 8];
#pragma unroll
    for (int fn = 0; fn < 8; ++fn) {
      bf16x8 bfr = *(const bf16x8*)&Bc[(klane * 128 + fn * 16 + li) * 8];
      acc[fn] = __builtin_amdgcn_mfma_f32_16x16x32_bf16(afr, bfr, acc[fn], 0, 0, 0);
    }
  }

  // ---- epilogue: kf (fp32 x, Killing Gram) + branch + store, coalesced ----
  // D frag: col = li (nn), row = klane*4 + r (within the wave's 16 g-rows)
#pragma unroll
  for (int r = 0; r < 4; ++r) {
    const int g = g0 + w * 16 + klane * 4 + r;
    const size_t base = ((size_t)(b * 512 + g)) * 16384 + n0 + li;
    float xk[8];
#pragma unroll
    for (int k = 0; k < 8; ++k) xk[k] = x[base + (size_t)k * 2048];
    // c_l = (G x)_l ; G: 12@(0,0),(4,4); -6@(0,4); 6@{1,3},{2,6},{5,7}
    const float c0 = 12.f * xk[0] - 6.f * xk[4];
    const float c4 = 12.f * xk[4] - 6.f * xk[0];
    const float c1 = 6.f * xk[3];
    const float c2 = 6.f * xk[6];
    const float c3 = 6.f * xk[1];
    const float c5 = 6.f * xk[7];
    const float c6 = 6.f * xk[2];
    const float c7 = 6.f * xk[5];
    const float kf = c0 * acc[0][r] + c1 * acc[1][r]
                   + c2 * acc[2][r] + c3 * acc[3][r]
                   + c4 * acc[4][r] + c5 * acc[5][r]
                   + c6 * acc[6][r] + c7 * acc[7][r];
#pragma unroll
    for (int k = 0; k < 8; ++k) {
      const float o = (kf <= 0.f) ? xk[k] : fmaf(kf, acc[k][r], xk[k]);
      out[base + (size_t)k * 2048] = o;
    }
  }
}

// ---------------- fallback: proven R2 kernel (ws too small) ----------------
__global__ __launch_bounds__(512, 4) void lnkill_fused(
    const float* __restrict__ x, const float* __restrict__ W,
    float* __restrict__ out) {
  __shared__ __align__(16) short ldsA[2][4096];
  __shared__ __align__(16) short ldsB[2][4096];

  const int tid  = threadIdx.x;
  const int lane = tid & 63;
  const int w    = tid >> 6;

  const int bid = blockIdx.x;
  const int l   = (bid & 7) * 512 + (bid >> 3);
  const int gt  = l & 3;
  const int nt  = (l >> 2) & 127;
  const int b   = l >> 9;
  const int g0  = gt * 128;
  const int n0  = nt * 16;

  const int cm = tid & 127;
  const int fg = tid >> 7;
  const float* xs   = x + (((size_t)(b * 512 + fg * 8)) * 8 + (cm >> 4)) * 2048
                        + n0 + (cm & 15);
  const float* Wrow = W + (size_t)(g0 + cm) * 512 + fg * 8;

  f32x4 acc[8] = {};

  {
    float xv[8];
#pragma unroll
    for (int j = 0; j < 8; ++j) xv[j] = xs[(size_t)j * 16384];
    float4 wv[2];
    const float4* wp = (const float4*)Wrow;
    wv[0] = wp[0]; wv[1] = wp[1];
    const float* wf = (const float*)wv;
    bf16x8 vb, va;
#pragma unroll
    for (int j = 0; j < 8; ++j) {
      vb[j] = (short)f2bf(xv[j]);
      va[j] = (short)f2bf(wf[j]);
    }
    *(bf16x8*)&ldsB[0][(fg * 128 + cm) * 8] = vb;
    *(bf16x8*)&ldsA[0][(fg * 128 + cm) * 8] = va;
  }
  __syncthreads();

  const int klane = lane >> 4;
  const int li    = lane & 15;

  for (int kt = 0; kt < 16; ++kt) {
    const int cur = kt & 1;
    float xv[8];
    float4 wv[2];
    if (kt < 15) {
      const float* xpn = xs + (size_t)(kt + 1) * 32 * 16384;
#pragma unroll
      for (int j = 0; j < 8; ++j) xv[j] = xpn[(size_t)j * 16384];
      const float4* wp = (const float4*)(Wrow + (kt + 1) * 32);
      wv[0] = wp[0]; wv[1] = wp[1];
    }
    {
      const short* Ac = ldsA[cur];
      const short* Bc = ldsB[cur];
      bf16x8 afr = *(const bf16x8*)&Ac[(klane * 128 + w * 16 + li) * 8];
#pragma unroll
      for (int fn = 0; fn < 8; ++fn) {
        bf16x8 bfr = *(const bf16x8*)&Bc[(klane * 128 + fn * 16 + li) * 8];
        acc[fn] = __builtin_amdgcn_mfma_f32_16x16x32_bf16(afr, bfr, acc[fn], 0, 0, 0);
      }
    }
    if (kt < 15) {
      const int nxt = cur ^ 1;
      const float* wf = (const float*)wv;
      bf16x8 vb, va;
#pragma unroll
      for (int j = 0; j < 8; ++j) {
        vb[j] = (short)f2bf(xv[j]);
        va[j] = (short)f2bf(wf[j]);
      }
      __syncthreads();
      *(bf16x8*)&ldsB[nxt][(fg * 128 + cm) * 8] = vb;
      *(bf16x8*)&ldsA[nxt][(fg * 128 + cm) * 8] = va;
      __syncthreads();
    }
  }

#pragma unroll
  for (int r = 0; r < 4; ++r) {
    const int g = g0 + w * 16 + klane * 4 + r;
    const size_t base = ((size_t)(b * 512 + g)) * 16384 + n0 + li;
    float xk[8];
#pragma unroll
    for (int k = 0; k < 8; ++k) xk[k] = x[base + (size_t)k * 2048];
    const float c0 = 12.f * xk[0] - 6.f * xk[4];
    const float c4 = 12.f * xk[4] - 6.f * xk[0];
    const float c1 = 6.f * xk[3];
    const float c2 = 6.f * xk[6];
    const float c3 = 6.f * xk[1];
    const float c5 = 6.f * xk[7];
    const float c6 = 6.f * xk[2];
    const float c7 = 6.f * xk[5];
    const float kf = c0 * acc[0][r] + c1 * acc[1][r]
                   + c2 * acc[2][r] + c3 * acc[3][r]
                   + c4 * acc[4][r] + c5 * acc[5][r]
                   + c6 * acc[6][r] + c7 * acc[7][r];
#pragma unroll
    for (int k = 0; k < 8; ++k) {
      const float o = (kf <= 0.f) ? xk[k] : fmaf(kf, acc[k][r], xk[k]);
      out[base + (size_t)k * 2048] = o;
    }
  }
}

extern "C" void kernel_launch(void* const* d_in, const int* in_sizes, int n_in,
                              void* d_out, int out_size, void* d_ws, size_t ws_size,
                              hipStream_t stream) {
  const float* x = (const float*)d_in[0];
  const float* W = (const float*)d_in[1];
  float* out = (float*)d_out;

  const size_t need = (size_t)512 * 1024 + (size_t)8388608 * 16;  // 0.5MB + 128MiB
  if (ws_size >= need) {
    short* wp = (short*)d_ws;                       // 512 KB
    short* xp = (short*)d_ws + 262144;              // after 512 KB
    prepack_w<<<dim3(128),   dim3(256), 0, stream>>>(W, wp);
    prepack_x<<<dim3(32768), dim3(256), 0, stream>>>(x, xp);
    lnkill_gemm_pk<<<dim3(4096), dim3(512), 0, stream>>>(xp, wp, x, out);
  } else {
    lnkill_fused<<<dim3(4096), dim3(512), 0, stream>>>(x, W, out);
  }
}